// Round 7
// baseline (6244.278 us; speedup 1.0000x reference)
//
#include <hip/hip_runtime.h>
#include <hip/hip_bf16.h>
#include <stdint.h>

// ESN sizes (fixed by the reference)
#define NRR     4096
#define NBATCH  16
#define NFEAT   12
#define SEQLEN  1024
#define ALPHA_C 0.6f

typedef _Float16 f16x8 __attribute__((ext_vector_type(8)));
typedef _Float16 f16x2 __attribute__((ext_vector_type(2)));
typedef float    f32x4 __attribute__((ext_vector_type(4)));
typedef unsigned long long u64;

constexpr int WGS    = 256;            // one WG per CU; 16 A-rows each
constexpr int TPB    = 512;            // 8 waves
constexpr int WAVES  = 8;
constexpr int KCHUNK = NRR / WAVES;    // 512 K per wave
constexpr int FRAGS  = KCHUNK / 32;    // 16 MFMAs per wave per step
constexpr int SLOTE  = NBATCH * NRR;   // fp16 elems per r-slot (128 KB)

#define SC_AGENT __HIP_MEMORY_SCOPE_AGENT

__device__ __forceinline__ unsigned ld_rlx(const unsigned* p) {
    return __hip_atomic_load(p, __ATOMIC_RELAXED, SC_AGENT);
}
__device__ __forceinline__ u64 ld_rlx64(const void* p) {
    return __hip_atomic_load((const u64*)p, __ATOMIC_RELAXED, SC_AGENT);
}
__device__ __forceinline__ void st_rlx(unsigned* p, unsigned v) {
    __hip_atomic_store(p, v, __ATOMIC_RELAXED, SC_AGENT);
}
__device__ __forceinline__ void st_rlx_f32(float* p, float v) {
    __hip_atomic_store(p, v, __ATOMIC_RELAXED, SC_AGENT);
}

// Single-hop flat grid barrier:
//  - __syncthreads: each wave's sc1 stores drained (vmcnt(0)) -> committed at L3
//  - tid0 relaxed-stores epoch into its own slot (16B-strided -> 32 cache lines)
//  - wave0 of EVERY WG polls all 256 slots itself (64 lanes x 4 slots),
//    tight spin for minimum detection latency; no master, no flag hop
//  - s_barrier releases the other waves
// Critical path: drain -> arrival visible -> self-detect. (R6's two-level
// design added master-detect + flag-visible, ~1 extra µs/step.)
__device__ __forceinline__ void gridbar(unsigned* slots, unsigned epoch,
                                        int wg, int tid, int lane, int wave,
                                        int use_inv) {
    __syncthreads();
    if (tid == 0) st_rlx(&slots[wg * 4], epoch);
    if (wave == 0) {
        const int i0 = lane * 4;  // 4 slots per lane, each at 16B stride
        for (;;) {
            unsigned a = ld_rlx(&slots[(i0 + 0) * 4]);
            unsigned b = ld_rlx(&slots[(i0 + 1) * 4]);
            unsigned c = ld_rlx(&slots[(i0 + 2) * 4]);
            unsigned d = ld_rlx(&slots[(i0 + 3) * 4]);
            bool ok = (a >= epoch) & (b >= epoch) & (c >= epoch) & (d >= epoch);
            if (__all(ok)) break;
        }
        // fallback path only (2-slot r ring): invalidate L1/L2 after all
        // producers committed, before any r-load of reused addresses
        if (use_inv && lane == 0)
            (void)__hip_atomic_load(&slots[wg * 4], __ATOMIC_ACQUIRE, SC_AGENT);
    }
    __syncthreads();
    asm volatile("" ::: "memory");  // keep r-loads below the poll exit
}

// Fast tanh: clamp + single v_exp + rcp. |err| ~1e-6, far below the fp16
// state quantization (~1e-3) already in the data path.
__device__ __forceinline__ float fast_tanh(float v) {
    float vc = fminf(fmaxf(v, -10.0f), 10.0f);
    float e  = __expf(2.0f * vc);
    return (e - 1.0f) * __builtin_amdgcn_rcpf(e + 1.0f);
}

__global__ __launch_bounds__(TPB, 1) void esn_persistent(
    const float* __restrict__ x,    // (16, 1024, 12)
    const float* __restrict__ r0,   // (1, 16, 4096)
    const float* __restrict__ A,    // (4096, 4096) row-major
    const float* __restrict__ Bm,   // (4096, 12)
    const float* __restrict__ bias, // (4096,)
    const float* __restrict__ Cw,   // (8, 4096)
    float* __restrict__ out,        // (16, 8)
    unsigned* __restrict__ slots,   // 256 arrival slots, 16B stride
    _Float16* __restrict__ rbuf,    // r ring: 1025 streaming slots (or 2 + INV)
    float* __restrict__ rfin,       // (16, 4096) fp32 final state
    int use_inv)                    // 0 = streaming ring, 1 = 2-slot ring + INV
{
    const int wg    = blockIdx.x;
    const int tid   = threadIdx.x;
    const int wave  = tid >> 6;
    const int lane  = tid & 63;
    const int l15   = lane & 15;   // A-frag row-in-tile / B-frag batch col
    const int g     = lane >> 4;   // k-group 0..3
    const int nbase = wg * 16;

    __shared__ float lds_red[WAVES][16][16];  // [w][batch][row]
    __shared__ float lds_x[2][NBATCH][NFEAT];
    __shared__ float lds_Bp[16][NFEAT];
    __shared__ float lds_bias[16];
    __shared__ float lds_out[4][128];

    // ---- A slice -> fp16 register fragments (A read exactly once) ----
    uint4 afrag[FRAGS];
    {
        const float* arow = A + (size_t)(nbase + l15) * NRR + wave * KCHUNK + g * 8;
#pragma unroll
        for (int i = 0; i < FRAGS; ++i) {
            const float4* p = (const float4*)(arow + i * 32);
            float4 f0 = p[0];
            float4 f1 = p[1];
            f16x8 h;
            h[0] = (_Float16)f0.x; h[1] = (_Float16)f0.y;
            h[2] = (_Float16)f0.z; h[3] = (_Float16)f0.w;
            h[4] = (_Float16)f1.x; h[5] = (_Float16)f1.y;
            h[6] = (_Float16)f1.z; h[7] = (_Float16)f1.w;
            afrag[i] = __builtin_bit_cast(uint4, h);
        }
    }

    // x prefetch mapping (tid<192): thread owns (batch xb, feat xf)
    const int xb = tid / NFEAT;
    const int xf = tid % NFEAT;
    const size_t xofs = (size_t)xb * SEQLEN * NFEAT + xf;

    if (tid < 16 * NFEAT)
        lds_Bp[xb][xf] = Bm[(size_t)(nbase + xb) * NFEAT + xf];
    if (tid < 16)
        lds_bias[tid] = bias[nbase + tid];
    if (tid < NBATCH * NFEAT)
        lds_x[0][xb][xf] = x[xofs];  // x[:, 0, :]

    // ---- master fp32 state: update thread tid<256 owns (batch=tid>>4, n=tid&15) ----
    const int ub = tid >> 4;
    const int un = tid & 15;
    float rm = 0.0f;
    if (tid < 256) {
        rm = r0[ub * NRR + nbase + un];
        float hi = __shfl_down(rm, 1);
        if (!(un & 1)) {
            f16x2 h2; h2[0] = (_Float16)rm; h2[1] = (_Float16)hi;
            st_rlx((unsigned*)(rbuf + (size_t)ub * NRR + nbase + un),
                   __builtin_bit_cast(unsigned, h2));
        }
    }

    gridbar(slots, 1u, wg, tid, lane, wave, use_inv);

    const size_t roff = (size_t)l15 * NRR + wave * KCHUNK + g * 8;

    for (int t = 0; t < SEQLEN; ++t) {
        // streaming ring: fresh slot every step -> plain cached loads are safe;
        // the 32 WGs sharing each XCD-L2 fetch each 128B line ONCE per step.
        const _Float16* rcur = rbuf + (size_t)(use_inv ? (t & 1) : t) * SLOTE;
        _Float16*       rnxt = rbuf + (size_t)(use_inv ? ((t + 1) & 1) : (t + 1)) * SLOTE;

        // kick x[t+1] prefetch
        float xp = 0.0f;
        if (tid < NBATCH * NFEAT && t + 1 < SEQLEN)
            xp = x[xofs + (size_t)(t + 1) * NFEAT];

        // S[n,b] partials over this wave's K-chunk; r via PLAIN cached uint4
        f32x4 acc = {0.f, 0.f, 0.f, 0.f};
        const _Float16* rrow = rcur + roff;
#pragma unroll
        for (int i = 0; i < FRAGS; ++i) {
            uint4 u = *(const uint4*)(rrow + i * 32);
            acc = __builtin_amdgcn_mfma_f32_16x16x32_f16(
                __builtin_bit_cast(f16x8, afrag[i]),
                __builtin_bit_cast(f16x8, u), acc, 0, 0, 0);
        }
        // D layout: col=lane&15 (batch), row=(lane>>4)*4+j. Transposed store
        // [w][batch][row] as one contiguous f32x4.
        *(f32x4*)&lds_red[wave][l15][g * 4] = acc;
        __syncthreads();

        if (tid < 256) {
            float s = 0.f;
#pragma unroll
            for (int w = 0; w < WAVES; ++w) s += lds_red[w][ub][un];
            float p = lds_bias[un];
            const float* xr = lds_x[t & 1][ub];
#pragma unroll
            for (int f = 0; f < NFEAT; ++f) p += lds_Bp[un][f] * xr[f];
            rm = (1.0f - ALPHA_C) * rm + ALPHA_C * fast_tanh(s + p);
            float hi = __shfl_down(rm, 1);
            if (!(un & 1)) {
                f16x2 h2; h2[0] = (_Float16)rm; h2[1] = (_Float16)hi;
                st_rlx((unsigned*)(rnxt + (size_t)ub * NRR + nbase + un),
                       __builtin_bit_cast(unsigned, h2));
            }
            if (t == SEQLEN - 1)
                st_rlx_f32(&rfin[(size_t)ub * NRR + nbase + un], rm);
        }
        // land x prefetch into the other LDS buffer
        if (tid < NBATCH * NFEAT && t + 1 < SEQLEN)
            lds_x[(t + 1) & 1][xb][xf] = xp;

        gridbar(slots, (unsigned)(t + 2), wg, tid, lane, wave, use_inv);
    }

    // ---- readout: out[b,o] = sum_k rfin[b,k] * Cw[o,k], by WG 0 ----
    // Final gridbar (epoch 1025) guarantees all rfin sc1 stores are at L3.
    if (wg == 0) {
        const int oi   = tid & 127;  // = b*8 + o
        const int part = tid >> 7;   // K-quarter
        const int b = oi >> 3, o = oi & 7;
        const float* rv = rfin + (size_t)b * NRR + part * (NRR / 4);
        const float* cv = Cw   + (size_t)o * NRR + part * (NRR / 4);
        float s = 0.f;
        for (int k = 0; k < NRR / 4; k += 2) {
            u64 u = ld_rlx64(rv + k);
            float ra = __builtin_bit_cast(float, (unsigned)u);
            float rb = __builtin_bit_cast(float, (unsigned)(u >> 32));
            s += ra * cv[k] + rb * cv[k + 1];
        }
        lds_out[part][oi] = s;
        __syncthreads();
        if (tid < 128)
            out[tid] = lds_out[0][tid] + lds_out[1][tid] + lds_out[2][tid] + lds_out[3][tid];
    }
}

extern "C" void kernel_launch(void* const* d_in, const int* in_sizes, int n_in,
                              void* d_out, int out_size, void* d_ws, size_t ws_size,
                              hipStream_t stream) {
    const float* x   = (const float*)d_in[0];
    const float* r0  = (const float*)d_in[1];
    const float* A   = (const float*)d_in[2];
    const float* Bm  = (const float*)d_in[3];
    const float* bv  = (const float*)d_in[4];
    const float* Cw  = (const float*)d_in[5];
    float*       out = (float*)d_out;

    char* ws = (char*)d_ws;
    unsigned*  slots = (unsigned*)ws;                       // 4 KB (256 slots x 16B)
    float*     rfin  = (float*)(ws + 4096);                 // 256 KB
    _Float16*  rbuf  = (_Float16*)(ws + 4096 + 262144);     // r ring

    // Streaming ring needs (SEQLEN+1) slots of 128 KB = ~134.6 MB total ws.
    const size_t need_stream = 4096 + 262144 + (size_t)(SEQLEN + 1) * SLOTE * 2;
    int use_inv = (ws_size >= need_stream) ? 0 : 1;

    // slots must start at 0 every call (incl. graph replays)
    hipMemsetAsync(ws, 0, 4096, stream);

    void* args[] = {(void*)&x, (void*)&r0, (void*)&A, (void*)&Bm, (void*)&bv, (void*)&Cw,
                    (void*)&out, (void*)&slots, (void*)&rbuf, (void*)&rfin,
                    (void*)&use_inv};
    hipError_t e = hipLaunchCooperativeKernel((const void*)esn_persistent,
                                              dim3(WGS), dim3(TPB), args, 0, stream);
    if (e != hipSuccess) {
        hipLaunchKernelGGL(esn_persistent, dim3(WGS), dim3(TPB), 0, stream,
                           x, r0, A, Bm, bv, Cw, out, slots, rbuf, rfin, use_inv);
    }
}